// Round 1
// baseline (509.678 us; speedup 1.0000x reference)
//
#include <hip/hip_runtime.h>

// Causal GQA prefill attention, flash-style, bf16 MFMA compute / fp32 softmax.
// B=2, S=2048, H=32, HKV=8, D=128, G=4.
// Kernel 1: transpose V -> Vt bf16 [b][hkv][D][S] in d_ws (8 MB).
// Kernel 2: block = (b, h, 128 q rows), 4 waves x 32 q rows, K-tile = 32.

#define B_   2
#define S_   2048
#define H_   32
#define HKV_ 8
#define D_   128
#define SCALEF 0.08838834764831845f
#define COEF  (SCALEF * 1.44269504088896340736f)   // scale * log2(e)

typedef float          f32x4 __attribute__((ext_vector_type(4)));
typedef __bf16         bf16x8 __attribute__((ext_vector_type(8)));
typedef unsigned short u16x8 __attribute__((ext_vector_type(8)));
typedef unsigned int   u32x4 __attribute__((ext_vector_type(4)));
typedef unsigned int   u32x2 __attribute__((ext_vector_type(2)));

#define MFMA16(a, b, c) __builtin_amdgcn_mfma_f32_16x16x32_bf16((a), (b), (c), 0, 0, 0)

#if defined(__has_builtin)
#if __has_builtin(__builtin_amdgcn_exp2f)
#define EXP2F(x) __builtin_amdgcn_exp2f(x)
#endif
#endif
#ifndef EXP2F
#define EXP2F(x) exp2f(x)
#endif

static __device__ __forceinline__ unsigned short f2bf(float f) {
  unsigned int u = __builtin_bit_cast(unsigned int, f);
  u = (u + 0x7fffu + ((u >> 16) & 1u)) >> 16;   // RNE; inputs finite
  return (unsigned short)u;
}

// DPP move (VALU pipe). CTRL: row_ror:n = 0x120|n, quad_perm[1,0,3,2] = 0xB1.
template <int CTRL>
static __device__ __forceinline__ float dppf(float v) {
  return __builtin_bit_cast(
      float, __builtin_amdgcn_update_dpp(0, __builtin_bit_cast(int, v), CTRL,
                                         0xF, 0xF, true));
}
static __device__ __forceinline__ float rowmax16(float v) {
  v = fmaxf(v, dppf<0x128>(v));
  v = fmaxf(v, dppf<0x124>(v));
  v = fmaxf(v, dppf<0x122>(v));
  v = fmaxf(v, dppf<0x121>(v));
  return v;
}
static __device__ __forceinline__ float rowsum16(float v) {
  v += dppf<0x128>(v);
  v += dppf<0x124>(v);
  v += dppf<0x122>(v);
  v += dppf<0x121>(v);
  return v;
}

// ---------------- Kernel 1: V -> Vt (bf16, [b][hkv][D][S]) ----------------
__global__ __launch_bounds__(256) void vt_transpose_kernel(
    const float* __restrict__ v, unsigned short* __restrict__ vt) {
  __shared__ float tile[32][65];  // +1 pad: conflict-free
  const int tid = threadIdx.x;
  const int s0 = blockIdx.x * 64;   // 32 s-tiles
  const int d0 = blockIdx.y * 32;   // 4 d-tiles
  const int bh = blockIdx.z;        // 16 (b*8+hkv)
  const float* src = v + (size_t)(bh >> 3) * S_ * (HKV_ * D_) + (bh & 7) * D_;
#pragma unroll
  for (int it = 0; it < 8; ++it) {
    int idx = it * 256 + tid;
    int sl = idx >> 5, dl = idx & 31;  // coalesced along d
    tile[dl][sl] = src[(size_t)(s0 + sl) * (HKV_ * D_) + d0 + dl];
  }
  __syncthreads();
  unsigned int* dst = (unsigned int*)vt;
#pragma unroll
  for (int it = 0; it < 4; ++it) {
    int idx = it * 256 + tid;
    int dl = idx >> 5, sp = idx & 31;
    unsigned int w = (unsigned int)f2bf(tile[dl][2 * sp]) |
                     ((unsigned int)f2bf(tile[dl][2 * sp + 1]) << 16);
    dst[(((size_t)bh * D_ + d0 + dl) * S_ + s0 + 2 * sp) >> 1] = w;
  }
}

// ---------------- Kernel 2: attention ----------------
// LDS strides (ushort): K rows 144 (128 data + 16 pad), Vt/P rows 48 (32+16).
#define KSTR 144
#define VSTR 48

__global__ __launch_bounds__(256) void attn_kernel(
    const float* __restrict__ qg, const float* __restrict__ kg,
    const unsigned short* __restrict__ vt, float* __restrict__ outg) {
  __shared__ unsigned short KL[32 * KSTR];        // 9216 B
  __shared__ unsigned short VL[128 * VSTR];       // 12288 B
  __shared__ unsigned short PL[4 * 32 * VSTR];    // 12288 B

  const int tid = threadIdx.x;
  const int wave = tid >> 6, lane = tid & 63;
  const int l15 = lane & 15, quad = lane >> 4;

  const int qb = (int)(gridDim.x - 1 - blockIdx.x);  // heavy blocks first
  const int b = (int)(blockIdx.y >> 5), h = (int)(blockIdx.y & 31);
  const int hkv = h >> 2;
  const int qbase = qb * 128 + wave * 32;  // this wave's 32 q rows

  // Q fragments (A-layout: A[m=lane&15][k=quad*8+j]), held in registers.
  u16x8 qf[2][4];
#pragma unroll
  for (int qt = 0; qt < 2; ++qt)
#pragma unroll
    for (int ch = 0; ch < 4; ++ch) {
      const float* p = qg + (size_t)(b * S_ + qbase + qt * 16 + l15) * (H_ * D_) +
                       h * D_ + ch * 32 + quad * 8;
      f32x4 x0 = *(const f32x4*)p;
      f32x4 x1 = *(const f32x4*)(p + 4);
      u16x8 t;
      t[0] = f2bf(x0[0]); t[1] = f2bf(x0[1]); t[2] = f2bf(x0[2]); t[3] = f2bf(x0[3]);
      t[4] = f2bf(x1[0]); t[5] = f2bf(x1[1]); t[6] = f2bf(x1[2]); t[7] = f2bf(x1[3]);
      qf[qt][ch] = t;
    }

  const f32x4 zero4 = {0.f, 0.f, 0.f, 0.f};
  const float NEG_INF = -__builtin_huge_valf();
  f32x4 acc[2][8];
#pragma unroll
  for (int qt = 0; qt < 2; ++qt)
#pragma unroll
    for (int dt = 0; dt < 8; ++dt) acc[qt][dt] = zero4;
  f32x4 mrow[2] = {{NEG_INF, NEG_INF, NEG_INF, NEG_INF},
                   {NEG_INF, NEG_INF, NEG_INF, NEG_INF}};
  f32x4 lrow[2] = {zero4, zero4};

  const int nkt = qb * 4 + 4;
  for (int kt = 0; kt < nkt; ++kt) {
    // ---- stage K tile: 32 kpos x 128 d, fp32->bf16, row-major padded ----
#pragma unroll
    for (int it = 0; it < 4; ++it) {
      int idx = it * 256 + tid;
      int kr = idx >> 5, c4 = idx & 31;
      const f32x4 kv = *(const f32x4*)(kg +
          (size_t)(b * S_ + kt * 32 + kr) * (HKV_ * D_) + hkv * D_ + c4 * 4);
      u32x2 w;
      w[0] = (unsigned int)f2bf(kv[0]) | ((unsigned int)f2bf(kv[1]) << 16);
      w[1] = (unsigned int)f2bf(kv[2]) | ((unsigned int)f2bf(kv[3]) << 16);
      *(u32x2*)&KL[kr * KSTR + c4 * 4] = w;
    }
    // ---- stage Vt tile: 128 d x 32 kpos (already bf16, k-major) ----
#pragma unroll
    for (int it = 0; it < 2; ++it) {
      int idx = it * 256 + tid;
      int dr = idx >> 2, c = idx & 3;
      u32x4 vv = *(const u32x4*)&vt[((size_t)(b * HKV_ + hkv) * D_ + dr) * S_ +
                                    kt * 32 + c * 8];
      *(u32x4*)&VL[dr * VSTR + c * 8] = vv;
    }
    __syncthreads();

    if (kt * 32 <= qbase + 31) {  // wave-uniform: skip fully-masked tiles
      // ---- QK^T: S[2 qt][2 n-halves], contraction over D in 4 chunks ----
      f32x4 sc[2][2] = {{zero4, zero4}, {zero4, zero4}};
#pragma unroll
      for (int h2 = 0; h2 < 2; ++h2)
#pragma unroll
        for (int ch = 0; ch < 4; ++ch) {
          u16x8 kf = *(const u16x8*)&KL[(h2 * 16 + l15) * KSTR + ch * 32 + quad * 8];
          bf16x8 kb = __builtin_bit_cast(bf16x8, kf);
          sc[0][h2] = MFMA16(__builtin_bit_cast(bf16x8, qf[0][ch]), kb, sc[0][h2]);
          sc[1][h2] = MFMA16(__builtin_bit_cast(bf16x8, qf[1][ch]), kb, sc[1][h2]);
        }
      const int kb0 = kt * 32;
#pragma unroll
      for (int qt = 0; qt < 2; ++qt) {
        const int qmin = qbase + qt * 16;
        // causal mask (only boundary tiles hit this)
#pragma unroll
        for (int h2 = 0; h2 < 2; ++h2) {
          if (kb0 + h2 * 16 + 15 > qmin) {
            int kgp = kb0 + h2 * 16 + l15;
#pragma unroll
            for (int r = 0; r < 4; ++r) {
              int qgp = qmin + quad * 4 + r;
              if (kgp > qgp) sc[qt][h2][r] = NEG_INF;
            }
          }
        }
        // online softmax (rows live on 16-lane DPP rows; 4 rows/lane via regs)
        f32x4 mold = mrow[qt], mnew, alpha;
#pragma unroll
        for (int r = 0; r < 4; ++r) {
          float mt = rowmax16(fmaxf(sc[qt][0][r], sc[qt][1][r]));
          float mn = fmaxf(mold[r], mt);
          mnew[r] = mn;
          alpha[r] = EXP2F((mold[r] - mn) * COEF);
          float p0 = EXP2F((sc[qt][0][r] - mn) * COEF);
          float p1 = EXP2F((sc[qt][1][r] - mn) * COEF);
          sc[qt][0][r] = p0;
          sc[qt][1][r] = p1;
          float rs = rowsum16(p0 + p1);
          lrow[qt][r] = lrow[qt][r] * alpha[r] + rs;
        }
        mrow[qt] = mnew;
#pragma unroll
        for (int dt = 0; dt < 8; ++dt)
#pragma unroll
          for (int r = 0; r < 4; ++r) acc[qt][dt][r] *= alpha[r];
        // P: C-layout -> LDS (bf16). Even lanes pack (k, k+1) via quad_perm swap.
#pragma unroll
        for (int h2 = 0; h2 < 2; ++h2)
#pragma unroll
          for (int r = 0; r < 4; ++r) {
            float mine = sc[qt][h2][r];
            float nb = dppf<0xB1>(mine);  // value from lane^1
            if (!(l15 & 1)) {
              unsigned int w =
                  (unsigned int)f2bf(mine) | ((unsigned int)f2bf(nb) << 16);
              *(unsigned int*)&PL[wave * (32 * VSTR) +
                                  (qt * 16 + quad * 4 + r) * VSTR + h2 * 16 + l15] = w;
            }
          }
      }
      // ---- PV: A = P (A-layout from LDS), B = Vt ----
      u16x8 pf0 = *(const u16x8*)&PL[wave * (32 * VSTR) + (l15)*VSTR + quad * 8];
      u16x8 pf1 = *(const u16x8*)&PL[wave * (32 * VSTR) + (16 + l15) * VSTR + quad * 8];
      bf16x8 pb0 = __builtin_bit_cast(bf16x8, pf0);
      bf16x8 pb1 = __builtin_bit_cast(bf16x8, pf1);
#pragma unroll
      for (int dt = 0; dt < 8; ++dt) {
        u16x8 vf = *(const u16x8*)&VL[(dt * 16 + l15) * VSTR + quad * 8];
        bf16x8 vb = __builtin_bit_cast(bf16x8, vf);
        acc[0][dt] = MFMA16(pb0, vb, acc[0][dt]);
        acc[1][dt] = MFMA16(pb1, vb, acc[1][dt]);
      }
    }
    __syncthreads();
  }

  // ---- epilogue: O /= l, store fp32 ----
#pragma unroll
  for (int qt = 0; qt < 2; ++qt) {
    f32x4 inv;
#pragma unroll
    for (int r = 0; r < 4; ++r) inv[r] = 1.0f / lrow[qt][r];
#pragma unroll
    for (int dt = 0; dt < 8; ++dt)
#pragma unroll
      for (int r = 0; r < 4; ++r)
        outg[(size_t)(b * S_ + qbase + qt * 16 + quad * 4 + r) * (H_ * D_) +
             h * D_ + dt * 16 + l15] = acc[qt][dt][r] * inv[r];
  }
}

extern "C" void kernel_launch(void* const* d_in, const int* in_sizes, int n_in,
                              void* d_out, int out_size, void* d_ws,
                              size_t ws_size, hipStream_t stream) {
  const float* q = (const float*)d_in[0];
  const float* k = (const float*)d_in[1];
  const float* v = (const float*)d_in[2];
  float* out = (float*)d_out;
  unsigned short* vtws = (unsigned short*)d_ws;  // 16*128*2048*2 = 8 MB

  dim3 g1(S_ / 64, D_ / 32, B_ * HKV_);  // 32 x 4 x 16
  vt_transpose_kernel<<<g1, 256, 0, stream>>>(v, vtws);

  dim3 g2(S_ / 128, B_ * H_);  // 16 x 64 = 1024 blocks
  attn_kernel<<<g2, 256, 0, stream>>>(q, k, vtws, out);
}

// Round 2
// 496.976 us; speedup vs baseline: 1.0256x; 1.0256x over previous
//
#include <hip/hip_runtime.h>

// Causal GQA prefill attention, flash-style, bf16 MFMA / fp32 softmax.
// B=2, S=2048, H=32, HKV=8, D=128, G=4.
// Prepass 1: K fp32 -> Kbf bf16 [b][hkv][S][D]      (d_ws +0,   8 MB)
// Prepass 2: V fp32 -> Vt  bf16 [b][hkv][D][S]      (d_ws +8MB, 8 MB)
// Main: block = (b,h,128 q rows), 4 waves x 32 q rows, K-tile 32.
//   Double-buffered LDS staging via global_load_lds (async), 1 barrier/iter.
//   K LDS chunks XOR-swizzled (on the global-address side) to kill the
//   16-way bank conflict of 256B rows; VL/PL unpadded 64B rows (8-way on
//   b128 == minimum phases, free).

#define B_   2
#define S_   2048
#define H_   32
#define HKV_ 8
#define D_   128
#define SCALEF 0.08838834764831845f
#define COEF  (SCALEF * 1.44269504088896340736f)   // scale * log2(e)

typedef float          f32x4 __attribute__((ext_vector_type(4)));
typedef __bf16         bf16x8 __attribute__((ext_vector_type(8)));
typedef unsigned short u16x8 __attribute__((ext_vector_type(8)));

#define MFMA16(a, b, c) __builtin_amdgcn_mfma_f32_16x16x32_bf16((a), (b), (c), 0, 0, 0)

#if defined(__has_builtin)
#if __has_builtin(__builtin_amdgcn_exp2f)
#define EXP2F(x) __builtin_amdgcn_exp2f(x)
#endif
#endif
#ifndef EXP2F
#define EXP2F(x) exp2f(x)
#endif

static __device__ __forceinline__ unsigned short f2bf(float f) {
  unsigned int u = __builtin_bit_cast(unsigned int, f);
  u = (u + 0x7fffu + ((u >> 16) & 1u)) >> 16;   // RNE; inputs finite
  return (unsigned short)u;
}

// async global->LDS, 16B per lane; lds dest = wave-uniform base + lane*16.
static __device__ __forceinline__ void load_lds16(const void* g, void* l) {
  __builtin_amdgcn_global_load_lds(
      (const __attribute__((address_space(1))) void*)g,
      (__attribute__((address_space(3))) void*)l, 16, 0, 0);
}

// DPP move (VALU pipe). CTRL: row_ror:n = 0x120|n, quad_perm[1,0,3,2] = 0xB1.
template <int CTRL>
static __device__ __forceinline__ float dppf(float v) {
  return __builtin_bit_cast(
      float, __builtin_amdgcn_update_dpp(0, __builtin_bit_cast(int, v), CTRL,
                                         0xF, 0xF, true));
}
static __device__ __forceinline__ float rowmax16(float v) {
  v = fmaxf(v, dppf<0x128>(v));
  v = fmaxf(v, dppf<0x124>(v));
  v = fmaxf(v, dppf<0x122>(v));
  v = fmaxf(v, dppf<0x121>(v));
  return v;
}
static __device__ __forceinline__ float rowsum16(float v) {
  v += dppf<0x128>(v);
  v += dppf<0x124>(v);
  v += dppf<0x122>(v);
  v += dppf<0x121>(v);
  return v;
}

// ------------- Prepass 1: K fp32 -> bf16 [b][hkv][S][D] -------------
__global__ __launch_bounds__(256) void k_convert_kernel(
    const float* __restrict__ k, unsigned short* __restrict__ kbf) {
  int t = blockIdx.x * 256 + threadIdx.x;
  int o = t * 8;                       // output-linear index
  int d = o & (D_ - 1);
  int s = (o >> 7) & (S_ - 1);
  int bh = o >> 18;                    // 0..15
  int b = bh >> 3, hkv = bh & 7;
  const float* src = k + (size_t)(b * S_ + s) * (HKV_ * D_) + hkv * D_ + d;
  f32x4 x0 = *(const f32x4*)src;
  f32x4 x1 = *(const f32x4*)(src + 4);
  u16x8 w;
  w[0] = f2bf(x0[0]); w[1] = f2bf(x0[1]); w[2] = f2bf(x0[2]); w[3] = f2bf(x0[3]);
  w[4] = f2bf(x1[0]); w[5] = f2bf(x1[1]); w[6] = f2bf(x1[2]); w[7] = f2bf(x1[3]);
  *(u16x8*)(kbf + o) = w;
}

// ------------- Prepass 2: V -> Vt (bf16, [b][hkv][D][S]) -------------
__global__ __launch_bounds__(256) void vt_transpose_kernel(
    const float* __restrict__ v, unsigned short* __restrict__ vt) {
  __shared__ float tile[32][65];  // +1 pad: conflict-free
  const int tid = threadIdx.x;
  const int s0 = blockIdx.x * 64;   // 32 s-tiles
  const int d0 = blockIdx.y * 32;   // 4 d-tiles
  const int bh = blockIdx.z;        // 16 (b*8+hkv)
  const float* src = v + (size_t)(bh >> 3) * S_ * (HKV_ * D_) + (bh & 7) * D_;
#pragma unroll
  for (int it = 0; it < 8; ++it) {
    int idx = it * 256 + tid;
    int sl = idx >> 5, dl = idx & 31;  // coalesced along d
    tile[dl][sl] = src[(size_t)(s0 + sl) * (HKV_ * D_) + d0 + dl];
  }
  __syncthreads();
  unsigned int* dst = (unsigned int*)vt;
#pragma unroll
  for (int it = 0; it < 4; ++it) {
    int idx = it * 256 + tid;
    int dl = idx >> 5, sp = idx & 31;
    unsigned int w = (unsigned int)f2bf(tile[dl][2 * sp]) |
                     ((unsigned int)f2bf(tile[dl][2 * sp + 1]) << 16);
    dst[(((size_t)bh * D_ + d0 + dl) * S_ + s0 + 2 * sp) >> 1] = w;
  }
}

// ------------- Main attention kernel -------------
__global__ __launch_bounds__(256) void attn_kernel(
    const float* __restrict__ qg, const unsigned short* __restrict__ kbfg,
    const unsigned short* __restrict__ vtg, float* __restrict__ outg) {
  // double-buffered K (32x128) and Vt (128x32) bf16 tiles, unpadded.
  __shared__ unsigned short KL[2][32 * 128];   // 2 x 8 KB
  __shared__ unsigned short VL[2][128 * 32];   // 2 x 8 KB
  __shared__ unsigned short PL[4][32 * 32];    // 4 x 2 KB (per-wave P)

  const int tid = threadIdx.x;
  const int wave = tid >> 6, lane = tid & 63;
  const int l15 = lane & 15, quad = lane >> 4;

  const int qb = (int)(gridDim.x - 1 - blockIdx.x);  // heavy blocks first
  const int b = (int)(blockIdx.y >> 5), h = (int)(blockIdx.y & 31);
  const int hkv = h >> 2;
  const int qbase = qb * 128 + wave * 32;

  const unsigned short* kbf = kbfg + (size_t)(b * HKV_ + hkv) * S_ * D_;
  const unsigned short* vtb = vtg + (size_t)(b * HKV_ + hkv) * D_ * S_;

  // Q fragments (A-layout: A[m=lane&15][k=quad*8+j]), registers, loaded once.
  u16x8 qf[2][4];
#pragma unroll
  for (int qt = 0; qt < 2; ++qt)
#pragma unroll
    for (int ch = 0; ch < 4; ++ch) {
      const float* p = qg + (size_t)(b * S_ + qbase + qt * 16 + l15) * (H_ * D_) +
                       h * D_ + ch * 32 + quad * 8;
      f32x4 x0 = *(const f32x4*)p;
      f32x4 x1 = *(const f32x4*)(p + 4);
      u16x8 t;
      t[0] = f2bf(x0[0]); t[1] = f2bf(x0[1]); t[2] = f2bf(x0[2]); t[3] = f2bf(x0[3]);
      t[4] = f2bf(x1[0]); t[5] = f2bf(x1[1]); t[6] = f2bf(x1[2]); t[7] = f2bf(x1[3]);
      qf[qt][ch] = t;
    }

  const f32x4 zero4 = {0.f, 0.f, 0.f, 0.f};
  const float NEG_INF = -__builtin_huge_valf();
  f32x4 acc[2][8];
#pragma unroll
  for (int qt = 0; qt < 2; ++qt)
#pragma unroll
    for (int dt = 0; dt < 8; ++dt) acc[qt][dt] = zero4;
  f32x4 mrow[2] = {{NEG_INF, NEG_INF, NEG_INF, NEG_INF},
                   {NEG_INF, NEG_INF, NEG_INF, NEG_INF}};
  f32x4 lrow[2] = {zero4, zero4};

  const int nkt = qb * 4 + 4;

  // ---- async staging of one K/Vt tile pair into buffer `buf` ----
  // K slot si (16B units): row kr=si>>4, phys chunk pc=si&15 holds logical
  // chunk pc^(kr&15) (XOR swizzle -> conflict-free b128 reads).
  auto stage = [&](int kt, int buf) {
#pragma unroll
    for (int j = 0; j < 2; ++j) {
      int si = wave * 128 + j * 64 + lane;
      int kr = si >> 4, pc = si & 15;
      int lc = pc ^ (kr & 15);
      load_lds16(kbf + (size_t)(kt * 32 + kr) * D_ + lc * 8,
                 &KL[buf][(wave * 128 + j * 64) * 8]);
    }
#pragma unroll
    for (int j = 0; j < 2; ++j) {
      int si = wave * 128 + j * 64 + lane;
      int dr = si >> 2, pc = si & 3;
      load_lds16(vtb + (size_t)dr * S_ + kt * 32 + pc * 8,
                 &VL[buf][(wave * 128 + j * 64) * 8]);
    }
  };

  stage(0, 0);
  __syncthreads();  // drains vmcnt: tile 0 resident

  for (int kt = 0; kt < nkt; ++kt) {
    const int cur = kt & 1;
    if (kt + 1 < nkt) stage(kt + 1, cur ^ 1);  // async, lands during compute

    if (kt * 32 <= qbase + 31) {  // wave-uniform: skip fully-masked tiles
      // ---- QK^T ----
      f32x4 sc[2][2] = {{zero4, zero4}, {zero4, zero4}};
#pragma unroll
      for (int h2 = 0; h2 < 2; ++h2) {
        const int row = h2 * 16 + l15;
#pragma unroll
        for (int ch = 0; ch < 4; ++ch) {
          const int pc = (ch * 4 + quad) ^ l15;  // un-swizzle
          u16x8 kf = *(const u16x8*)&KL[cur][row * D_ + pc * 8];
          bf16x8 kb = __builtin_bit_cast(bf16x8, kf);
          sc[0][h2] = MFMA16(__builtin_bit_cast(bf16x8, qf[0][ch]), kb, sc[0][h2]);
          sc[1][h2] = MFMA16(__builtin_bit_cast(bf16x8, qf[1][ch]), kb, sc[1][h2]);
        }
      }
      const int kb0 = kt * 32;
#pragma unroll
      for (int qt = 0; qt < 2; ++qt) {
        const int qmin = qbase + qt * 16;
        // causal mask (boundary tiles only)
#pragma unroll
        for (int h2 = 0; h2 < 2; ++h2) {
          if (kb0 + h2 * 16 + 15 > qmin) {
            int kgp = kb0 + h2 * 16 + l15;
#pragma unroll
            for (int r = 0; r < 4; ++r) {
              int qgp = qmin + quad * 4 + r;
              if (kgp > qgp) sc[qt][h2][r] = NEG_INF;
            }
          }
        }
        // online softmax (16-lane DPP rows; 4 rows/lane in regs)
        f32x4 mold = mrow[qt], mnew, alpha;
#pragma unroll
        for (int r = 0; r < 4; ++r) {
          float mt = rowmax16(fmaxf(sc[qt][0][r], sc[qt][1][r]));
          float mn = fmaxf(mold[r], mt);
          mnew[r] = mn;
          alpha[r] = EXP2F((mold[r] - mn) * COEF);
          float p0 = EXP2F((sc[qt][0][r] - mn) * COEF);
          float p1 = EXP2F((sc[qt][1][r] - mn) * COEF);
          sc[qt][0][r] = p0;
          sc[qt][1][r] = p1;
          float rs = rowsum16(p0 + p1);
          lrow[qt][r] = lrow[qt][r] * alpha[r] + rs;
        }
        mrow[qt] = mnew;
#pragma unroll
        for (int dt = 0; dt < 8; ++dt)
#pragma unroll
          for (int r = 0; r < 4; ++r) acc[qt][dt][r] *= alpha[r];
        // P: C-layout -> LDS bf16 (even lanes pack (k,k+1) via quad_perm swap)
#pragma unroll
        for (int h2 = 0; h2 < 2; ++h2)
#pragma unroll
          for (int r = 0; r < 4; ++r) {
            float mine = sc[qt][h2][r];
            float nb = dppf<0xB1>(mine);  // value from lane^1
            if (!(l15 & 1)) {
              unsigned int w =
                  (unsigned int)f2bf(mine) | ((unsigned int)f2bf(nb) << 16);
              *(unsigned int*)&PL[wave][(qt * 16 + quad * 4 + r) * 32 +
                                        h2 * 16 + l15] = w;
            }
          }
      }
      // ---- PV: A = P (A-layout from LDS), B = Vt ----
      u16x8 pf0 = *(const u16x8*)&PL[wave][l15 * 32 + quad * 8];
      u16x8 pf1 = *(const u16x8*)&PL[wave][(16 + l15) * 32 + quad * 8];
      bf16x8 pb0 = __builtin_bit_cast(bf16x8, pf0);
      bf16x8 pb1 = __builtin_bit_cast(bf16x8, pf1);
#pragma unroll
      for (int dt = 0; dt < 8; ++dt) {
        u16x8 vf = *(const u16x8*)&VL[cur][(dt * 16 + l15) * 32 + quad * 8];
        bf16x8 vb = __builtin_bit_cast(bf16x8, vf);
        acc[0][dt] = MFMA16(pb0, vb, acc[0][dt]);
        acc[1][dt] = MFMA16(pb1, vb, acc[1][dt]);
      }
    }
    __syncthreads();  // drains vmcnt (next tile resident) + publishes buffers
  }

  // ---- epilogue: O /= l, store fp32 ----
#pragma unroll
  for (int qt = 0; qt < 2; ++qt) {
    f32x4 inv;
#pragma unroll
    for (int r = 0; r < 4; ++r) inv[r] = 1.0f / lrow[qt][r];
#pragma unroll
    for (int dt = 0; dt < 8; ++dt)
#pragma unroll
      for (int r = 0; r < 4; ++r)
        outg[(size_t)(b * S_ + qbase + qt * 16 + quad * 4 + r) * (H_ * D_) +
             h * D_ + dt * 16 + l15] = acc[qt][dt][r] * inv[r];
  }
}

extern "C" void kernel_launch(void* const* d_in, const int* in_sizes, int n_in,
                              void* d_out, int out_size, void* d_ws,
                              size_t ws_size, hipStream_t stream) {
  const float* q = (const float*)d_in[0];
  const float* k = (const float*)d_in[1];
  const float* v = (const float*)d_in[2];
  float* out = (float*)d_out;
  unsigned short* kws = (unsigned short*)d_ws;            // 8 MB Kbf
  unsigned short* vtws = kws + (size_t)B_ * HKV_ * S_ * D_;  // 8 MB Vt

  k_convert_kernel<<<(B_ * S_ * HKV_ * D_ / 8) / 256, 256, 0, stream>>>(k, kws);

  dim3 g1(S_ / 64, D_ / 32, B_ * HKV_);
  vt_transpose_kernel<<<g1, 256, 0, stream>>>(v, vtws);

  dim3 g2(S_ / 128, B_ * H_);  // 16 x 64 = 1024 blocks
  attn_kernel<<<g2, 256, 0, stream>>>(q, kws, vtws, out);
}

// Round 3
// 453.767 us; speedup vs baseline: 1.1232x; 1.0952x over previous
//
#include <hip/hip_runtime.h>

// Causal GQA prefill attention, flash-style, bf16 MFMA / fp32 softmax.
// B=2, S=2048, H=32, HKV=8, D=128, G=4.
// Prepass 1: K fp32 -> Kbf bf16 [b][hkv][S][D]      (d_ws +0,   8 MB)
// Prepass 2: V fp32 -> Vt  bf16 [b][hkv][D][S]      (d_ws +8MB, 8 MB)
// Main: 512 blocks, each does TWO 128-row q-tiles (qb=x and qb=15-x) in
// sequential phases -> every block runs exactly 68 k-iterations (uniform
// per-CU load; fixes the x-major grid -> same-qb-per-CU imbalance that
// pinned rounds 1-2 at ~432 us).

#define B_   2
#define S_   2048
#define H_   32
#define HKV_ 8
#define D_   128
#define SCALEF 0.08838834764831845f
#define COEF  (SCALEF * 1.44269504088896340736f)   // scale * log2(e)

typedef float          f32x4 __attribute__((ext_vector_type(4)));
typedef __bf16         bf16x8 __attribute__((ext_vector_type(8)));
typedef unsigned short u16x8 __attribute__((ext_vector_type(8)));

#define MFMA16(a, b, c) __builtin_amdgcn_mfma_f32_16x16x32_bf16((a), (b), (c), 0, 0, 0)

#if defined(__has_builtin)
#if __has_builtin(__builtin_amdgcn_exp2f)
#define EXP2F(x) __builtin_amdgcn_exp2f(x)
#endif
#endif
#ifndef EXP2F
#define EXP2F(x) exp2f(x)
#endif

static __device__ __forceinline__ unsigned short f2bf(float f) {
  unsigned int u = __builtin_bit_cast(unsigned int, f);
  u = (u + 0x7fffu + ((u >> 16) & 1u)) >> 16;   // RNE; inputs finite
  return (unsigned short)u;
}

// async global->LDS, 16B per lane; lds dest = wave-uniform base + lane*16.
static __device__ __forceinline__ void load_lds16(const void* g, void* l) {
  __builtin_amdgcn_global_load_lds(
      (const __attribute__((address_space(1))) void*)g,
      (__attribute__((address_space(3))) void*)l, 16, 0, 0);
}

// DPP move (VALU pipe). CTRL: row_ror:n = 0x120|n, quad_perm[1,0,3,2] = 0xB1.
template <int CTRL>
static __device__ __forceinline__ float dppf(float v) {
  return __builtin_bit_cast(
      float, __builtin_amdgcn_update_dpp(0, __builtin_bit_cast(int, v), CTRL,
                                         0xF, 0xF, true));
}
static __device__ __forceinline__ float rowmax16(float v) {
  v = fmaxf(v, dppf<0x128>(v));
  v = fmaxf(v, dppf<0x124>(v));
  v = fmaxf(v, dppf<0x122>(v));
  v = fmaxf(v, dppf<0x121>(v));
  return v;
}
static __device__ __forceinline__ float rowsum16(float v) {
  v += dppf<0x128>(v);
  v += dppf<0x124>(v);
  v += dppf<0x122>(v);
  v += dppf<0x121>(v);
  return v;
}

// ------------- Prepass 1: K fp32 -> bf16 [b][hkv][S][D] -------------
__global__ __launch_bounds__(256) void k_convert_kernel(
    const float* __restrict__ k, unsigned short* __restrict__ kbf) {
  int t = blockIdx.x * 256 + threadIdx.x;
  int o = t * 8;                       // output-linear index
  int d = o & (D_ - 1);
  int s = (o >> 7) & (S_ - 1);
  int bh = o >> 18;                    // 0..15
  int b = bh >> 3, hkv = bh & 7;
  const float* src = k + (size_t)(b * S_ + s) * (HKV_ * D_) + hkv * D_ + d;
  f32x4 x0 = *(const f32x4*)src;
  f32x4 x1 = *(const f32x4*)(src + 4);
  u16x8 w;
  w[0] = f2bf(x0[0]); w[1] = f2bf(x0[1]); w[2] = f2bf(x0[2]); w[3] = f2bf(x0[3]);
  w[4] = f2bf(x1[0]); w[5] = f2bf(x1[1]); w[6] = f2bf(x1[2]); w[7] = f2bf(x1[3]);
  *(u16x8*)(kbf + o) = w;
}

// ------------- Prepass 2: V -> Vt (bf16, [b][hkv][D][S]) -------------
__global__ __launch_bounds__(256) void vt_transpose_kernel(
    const float* __restrict__ v, unsigned short* __restrict__ vt) {
  __shared__ float tile[32][65];  // +1 pad: conflict-free
  const int tid = threadIdx.x;
  const int s0 = blockIdx.x * 64;   // 32 s-tiles
  const int d0 = blockIdx.y * 32;   // 4 d-tiles
  const int bh = blockIdx.z;        // 16 (b*8+hkv)
  const float* src = v + (size_t)(bh >> 3) * S_ * (HKV_ * D_) + (bh & 7) * D_;
#pragma unroll
  for (int it = 0; it < 8; ++it) {
    int idx = it * 256 + tid;
    int sl = idx >> 5, dl = idx & 31;  // coalesced along d
    tile[dl][sl] = src[(size_t)(s0 + sl) * (HKV_ * D_) + d0 + dl];
  }
  __syncthreads();
  unsigned int* dst = (unsigned int*)vt;
#pragma unroll
  for (int it = 0; it < 4; ++it) {
    int idx = it * 256 + tid;
    int dl = idx >> 5, sp = idx & 31;
    unsigned int w = (unsigned int)f2bf(tile[dl][2 * sp]) |
                     ((unsigned int)f2bf(tile[dl][2 * sp + 1]) << 16);
    dst[(((size_t)bh * D_ + d0 + dl) * S_ + s0 + 2 * sp) >> 1] = w;
  }
}

// ------------- Main attention kernel -------------
__global__ __launch_bounds__(256) void attn_kernel(
    const float* __restrict__ qg, const unsigned short* __restrict__ kbfg,
    const unsigned short* __restrict__ vtg, float* __restrict__ outg) {
  // double-buffered K (32x128) and Vt (128x32) bf16 tiles, unpadded.
  __shared__ unsigned short KL[2][32 * 128];   // 2 x 8 KB
  __shared__ unsigned short VL[2][128 * 32];   // 2 x 8 KB
  __shared__ unsigned short PL[4][32 * 32];    // 4 x 2 KB (per-wave P)

  const int tid = threadIdx.x;
  const int wave = tid >> 6, lane = tid & 63;
  const int l15 = lane & 15, quad = lane >> 4;

  const int xb = (int)blockIdx.x;  // 0..7: handles qb = xb and qb = 15-xb
  const int b = (int)(blockIdx.y >> 5), h = (int)(blockIdx.y & 31);
  const int hkv = h >> 2;

  const unsigned short* kbf = kbfg + (size_t)(b * HKV_ + hkv) * S_ * D_;
  const unsigned short* vtb = vtg + (size_t)(b * HKV_ + hkv) * D_ * S_;

  const f32x4 zero4 = {0.f, 0.f, 0.f, 0.f};
  const float NEG_INF = -__builtin_huge_valf();

  // ---- async staging of one K/Vt tile pair into buffer `buf` ----
  // K slot si (16B units): row kr=si>>4, phys chunk pc=si&15 holds logical
  // chunk pc^(kr&15) (XOR swizzle -> conflict-free b128 reads).
  auto stage = [&](int kt, int buf) {
#pragma unroll
    for (int j = 0; j < 2; ++j) {
      int si = wave * 128 + j * 64 + lane;
      int kr = si >> 4, pc = si & 15;
      int lc = pc ^ (kr & 15);
      load_lds16(kbf + (size_t)(kt * 32 + kr) * D_ + lc * 8,
                 &KL[buf][(wave * 128 + j * 64) * 8]);
    }
#pragma unroll
    for (int j = 0; j < 2; ++j) {
      int si = wave * 128 + j * 64 + lane;
      int dr = si >> 2, pc = si & 3;
      load_lds16(vtb + (size_t)dr * S_ + kt * 32 + pc * 8,
                 &VL[buf][(wave * 128 + j * 64) * 8]);
    }
  };

  for (int ph = 0; ph < 2; ++ph) {
    const int qb = ph ? (15 - xb) : xb;
    const int qbase = qb * 128 + wave * 32;

    // Q fragments (A-layout: A[m=lane&15][k=quad*8+j]), registers.
    u16x8 qf[2][4];
#pragma unroll
    for (int qt = 0; qt < 2; ++qt)
#pragma unroll
      for (int ch = 0; ch < 4; ++ch) {
        const float* p = qg +
            (size_t)(b * S_ + qbase + qt * 16 + l15) * (H_ * D_) +
            h * D_ + ch * 32 + quad * 8;
        f32x4 x0 = *(const f32x4*)p;
        f32x4 x1 = *(const f32x4*)(p + 4);
        u16x8 t;
        t[0] = f2bf(x0[0]); t[1] = f2bf(x0[1]); t[2] = f2bf(x0[2]); t[3] = f2bf(x0[3]);
        t[4] = f2bf(x1[0]); t[5] = f2bf(x1[1]); t[6] = f2bf(x1[2]); t[7] = f2bf(x1[3]);
        qf[qt][ch] = t;
      }

    f32x4 acc[2][8];
#pragma unroll
    for (int qt = 0; qt < 2; ++qt)
#pragma unroll
      for (int dt = 0; dt < 8; ++dt) acc[qt][dt] = zero4;
    f32x4 mrow[2] = {{NEG_INF, NEG_INF, NEG_INF, NEG_INF},
                     {NEG_INF, NEG_INF, NEG_INF, NEG_INF}};
    f32x4 lrow[2] = {zero4, zero4};

    const int nkt = qb * 4 + 4;

    stage(0, 0);
    __syncthreads();  // drains vmcnt: tile 0 resident

    for (int kt = 0; kt < nkt; ++kt) {
      const int cur = kt & 1;
      if (kt + 1 < nkt) stage(kt + 1, cur ^ 1);  // async, lands during compute

      if (kt * 32 <= qbase + 31) {  // wave-uniform: skip fully-masked tiles
        // ---- QK^T ----
        f32x4 sc[2][2] = {{zero4, zero4}, {zero4, zero4}};
#pragma unroll
        for (int h2 = 0; h2 < 2; ++h2) {
          const int row = h2 * 16 + l15;
#pragma unroll
          for (int ch = 0; ch < 4; ++ch) {
            const int pc = (ch * 4 + quad) ^ l15;  // un-swizzle
            u16x8 kf = *(const u16x8*)&KL[cur][row * D_ + pc * 8];
            bf16x8 kb = __builtin_bit_cast(bf16x8, kf);
            sc[0][h2] = MFMA16(__builtin_bit_cast(bf16x8, qf[0][ch]), kb, sc[0][h2]);
            sc[1][h2] = MFMA16(__builtin_bit_cast(bf16x8, qf[1][ch]), kb, sc[1][h2]);
          }
        }
        const int kb0 = kt * 32;
#pragma unroll
        for (int qt = 0; qt < 2; ++qt) {
          const int qmin = qbase + qt * 16;
          // causal mask (boundary tiles only)
#pragma unroll
          for (int h2 = 0; h2 < 2; ++h2) {
            if (kb0 + h2 * 16 + 15 > qmin) {
              int kgp = kb0 + h2 * 16 + l15;
#pragma unroll
              for (int r = 0; r < 4; ++r) {
                int qgp = qmin + quad * 4 + r;
                if (kgp > qgp) sc[qt][h2][r] = NEG_INF;
              }
            }
          }
          // online softmax (16-lane DPP rows; 4 rows/lane in regs)
          f32x4 mold = mrow[qt], mnew, alpha;
#pragma unroll
          for (int r = 0; r < 4; ++r) {
            float mt = rowmax16(fmaxf(sc[qt][0][r], sc[qt][1][r]));
            float mn = fmaxf(mold[r], mt);
            mnew[r] = mn;
            alpha[r] = EXP2F((mold[r] - mn) * COEF);
            float p0 = EXP2F((sc[qt][0][r] - mn) * COEF);
            float p1 = EXP2F((sc[qt][1][r] - mn) * COEF);
            sc[qt][0][r] = p0;
            sc[qt][1][r] = p1;
            float rs = rowsum16(p0 + p1);
            lrow[qt][r] = lrow[qt][r] * alpha[r] + rs;
          }
          mrow[qt] = mnew;
#pragma unroll
          for (int dt = 0; dt < 8; ++dt)
#pragma unroll
            for (int r = 0; r < 4; ++r) acc[qt][dt][r] *= alpha[r];
          // P: C-layout -> LDS bf16 (even lanes pack (k,k+1) via quad_perm)
#pragma unroll
          for (int h2 = 0; h2 < 2; ++h2)
#pragma unroll
            for (int r = 0; r < 4; ++r) {
              float mine = sc[qt][h2][r];
              float nb = dppf<0xB1>(mine);  // value from lane^1
              if (!(l15 & 1)) {
                unsigned int w =
                    (unsigned int)f2bf(mine) | ((unsigned int)f2bf(nb) << 16);
                *(unsigned int*)&PL[wave][(qt * 16 + quad * 4 + r) * 32 +
                                          h2 * 16 + l15] = w;
              }
            }
        }
        // ---- PV: A = P (A-layout from LDS), B = Vt ----
        u16x8 pf0 = *(const u16x8*)&PL[wave][l15 * 32 + quad * 8];
        u16x8 pf1 = *(const u16x8*)&PL[wave][(16 + l15) * 32 + quad * 8];
        bf16x8 pb0 = __builtin_bit_cast(bf16x8, pf0);
        bf16x8 pb1 = __builtin_bit_cast(bf16x8, pf1);
#pragma unroll
        for (int dt = 0; dt < 8; ++dt) {
          u16x8 vf = *(const u16x8*)&VL[cur][(dt * 16 + l15) * 32 + quad * 8];
          bf16x8 vb = __builtin_bit_cast(bf16x8, vf);
          acc[0][dt] = MFMA16(pb0, vb, acc[0][dt]);
          acc[1][dt] = MFMA16(pb1, vb, acc[1][dt]);
        }
      }
      __syncthreads();  // drains vmcnt (next tile resident) + publishes bufs
    }

    // ---- epilogue: O /= l, store fp32 (no LDS use -> safe across phases)
#pragma unroll
    for (int qt = 0; qt < 2; ++qt) {
      f32x4 inv;
#pragma unroll
      for (int r = 0; r < 4; ++r) inv[r] = 1.0f / lrow[qt][r];
#pragma unroll
      for (int dt = 0; dt < 8; ++dt)
#pragma unroll
        for (int r = 0; r < 4; ++r)
          outg[(size_t)(b * S_ + qbase + qt * 16 + quad * 4 + r) * (H_ * D_) +
               h * D_ + dt * 16 + l15] = acc[qt][dt][r] * inv[r];
    }
  }
}

extern "C" void kernel_launch(void* const* d_in, const int* in_sizes, int n_in,
                              void* d_out, int out_size, void* d_ws,
                              size_t ws_size, hipStream_t stream) {
  const float* q = (const float*)d_in[0];
  const float* k = (const float*)d_in[1];
  const float* v = (const float*)d_in[2];
  float* out = (float*)d_out;
  unsigned short* kws = (unsigned short*)d_ws;               // 8 MB Kbf
  unsigned short* vtws = kws + (size_t)B_ * HKV_ * S_ * D_;  // 8 MB Vt

  k_convert_kernel<<<(B_ * S_ * HKV_ * D_ / 8) / 256, 256, 0, stream>>>(k, kws);

  dim3 g1(S_ / 64, D_ / 32, B_ * HKV_);
  vt_transpose_kernel<<<g1, 256, 0, stream>>>(v, vtws);

  dim3 g2(8, B_ * H_);  // 8 x 64 = 512 uniform blocks (68 k-iters each)
  attn_kernel<<<g2, 256, 0, stream>>>(q, kws, vtws, out);
}

// Round 4
// 286.173 us; speedup vs baseline: 1.7810x; 1.5856x over previous
//
#include <hip/hip_runtime.h>

// Causal GQA prefill attention, flash-style, bf16 MFMA / fp32 softmax.
// B=2, S=2048, H=32, HKV=8, D=128, G=4.
// Prepass 1: K fp32 -> Kbf bf16 [b][hkv][S][D]      (d_ws +0,   8 MB)
// Prepass 2: V fp32 -> Vt  bf16 [b][hkv][D][S]      (d_ws +8MB, 8 MB)
// Main (round 4): 1024 blocks = 16 causal pairs (qb=x, qb=31-x) x 64 bh.
//   64 q-rows per block phase, 16 rows per wave -> 4 blocks/CU, 16 waves/CU
//   (4 waves/SIMD) to hide the per-iteration latency chain that pinned
//   rounds 1-3 (~13k cyc/iter wall at 2 blocks/CU). Q pre-scaled by
//   SCALE*log2e so softmax exp arg is a single subtract. VL chunk-XOR
//   swizzle + PL stride-40 padding -> 2-way (free) LDS access.

#define B_   2
#define S_   2048
#define H_   32
#define HKV_ 8
#define D_   128
#define SCALEF 0.08838834764831845f
#define COEF  (SCALEF * 1.44269504088896340736f)   // scale * log2(e)

typedef float          f32x4 __attribute__((ext_vector_type(4)));
typedef __bf16         bf16x8 __attribute__((ext_vector_type(8)));
typedef unsigned short u16x8 __attribute__((ext_vector_type(8)));

#define MFMA16(a, b, c) __builtin_amdgcn_mfma_f32_16x16x32_bf16((a), (b), (c), 0, 0, 0)

#if defined(__has_builtin)
#if __has_builtin(__builtin_amdgcn_exp2f)
#define EXP2F(x) __builtin_amdgcn_exp2f(x)
#endif
#endif
#ifndef EXP2F
#define EXP2F(x) exp2f(x)
#endif

static __device__ __forceinline__ unsigned short f2bf(float f) {
  unsigned int u = __builtin_bit_cast(unsigned int, f);
  u = (u + 0x7fffu + ((u >> 16) & 1u)) >> 16;   // RNE; inputs finite
  return (unsigned short)u;
}

// async global->LDS, 16B per lane; lds dest = wave-uniform base + lane*16.
static __device__ __forceinline__ void load_lds16(const void* g, void* l) {
  __builtin_amdgcn_global_load_lds(
      (const __attribute__((address_space(1))) void*)g,
      (__attribute__((address_space(3))) void*)l, 16, 0, 0);
}

// DPP move (VALU pipe). CTRL: row_ror:n = 0x120|n, quad_perm[1,0,3,2] = 0xB1.
template <int CTRL>
static __device__ __forceinline__ float dppf(float v) {
  return __builtin_bit_cast(
      float, __builtin_amdgcn_update_dpp(0, __builtin_bit_cast(int, v), CTRL,
                                         0xF, 0xF, true));
}
static __device__ __forceinline__ float rowmax16(float v) {
  v = fmaxf(v, dppf<0x128>(v));
  v = fmaxf(v, dppf<0x124>(v));
  v = fmaxf(v, dppf<0x122>(v));
  v = fmaxf(v, dppf<0x121>(v));
  return v;
}
static __device__ __forceinline__ float rowsum16(float v) {
  v += dppf<0x128>(v);
  v += dppf<0x124>(v);
  v += dppf<0x122>(v);
  v += dppf<0x121>(v);
  return v;
}

// ------------- Prepass 1: K fp32 -> bf16 [b][hkv][S][D] -------------
__global__ __launch_bounds__(256) void k_convert_kernel(
    const float* __restrict__ k, unsigned short* __restrict__ kbf) {
  int t = blockIdx.x * 256 + threadIdx.x;
  int o = t * 8;                       // output-linear index
  int d = o & (D_ - 1);
  int s = (o >> 7) & (S_ - 1);
  int bh = o >> 18;                    // 0..15
  int b = bh >> 3, hkv = bh & 7;
  const float* src = k + (size_t)(b * S_ + s) * (HKV_ * D_) + hkv * D_ + d;
  f32x4 x0 = *(const f32x4*)src;
  f32x4 x1 = *(const f32x4*)(src + 4);
  u16x8 w;
  w[0] = f2bf(x0[0]); w[1] = f2bf(x0[1]); w[2] = f2bf(x0[2]); w[3] = f2bf(x0[3]);
  w[4] = f2bf(x1[0]); w[5] = f2bf(x1[1]); w[6] = f2bf(x1[2]); w[7] = f2bf(x1[3]);
  *(u16x8*)(kbf + o) = w;
}

// ------------- Prepass 2: V -> Vt (bf16, [b][hkv][D][S]) -------------
__global__ __launch_bounds__(256) void vt_transpose_kernel(
    const float* __restrict__ v, unsigned short* __restrict__ vt) {
  __shared__ float tile[32][65];  // +1 pad: conflict-free
  const int tid = threadIdx.x;
  const int s0 = blockIdx.x * 64;   // 32 s-tiles
  const int d0 = blockIdx.y * 32;   // 4 d-tiles
  const int bh = blockIdx.z;        // 16 (b*8+hkv)
  const float* src = v + (size_t)(bh >> 3) * S_ * (HKV_ * D_) + (bh & 7) * D_;
#pragma unroll
  for (int it = 0; it < 8; ++it) {
    int idx = it * 256 + tid;
    int sl = idx >> 5, dl = idx & 31;  // coalesced along d
    tile[dl][sl] = src[(size_t)(s0 + sl) * (HKV_ * D_) + d0 + dl];
  }
  __syncthreads();
  unsigned int* dst = (unsigned int*)vt;
#pragma unroll
  for (int it = 0; it < 4; ++it) {
    int idx = it * 256 + tid;
    int dl = idx >> 5, sp = idx & 31;
    unsigned int w = (unsigned int)f2bf(tile[dl][2 * sp]) |
                     ((unsigned int)f2bf(tile[dl][2 * sp + 1]) << 16);
    dst[(((size_t)bh * D_ + d0 + dl) * S_ + s0 + 2 * sp) >> 1] = w;
  }
}

// ------------- Main attention kernel -------------
#define PSTR 40  // PL row stride in shorts (80 B, 16B-aligned, 2-way banks)

__global__ __launch_bounds__(256, 4) void attn_kernel(
    const float* __restrict__ qg, const unsigned short* __restrict__ kbfg,
    const unsigned short* __restrict__ vtg, float* __restrict__ outg) {
  __shared__ unsigned short KL[2][32 * 128];   // 2 x 8 KB
  __shared__ unsigned short VL[2][128 * 32];   // 2 x 8 KB (chunk-swizzled)
  __shared__ unsigned short PL[4][16 * PSTR];  // 4 x 1.25 KB (per-wave P)

  const int tid = threadIdx.x;
  const int wave = tid >> 6, lane = tid & 63;
  const int l15 = lane & 15, quad = lane >> 4;

  const int xb = (int)blockIdx.x;  // 0..15: handles qb = xb and qb = 31-xb
  const int b = (int)(blockIdx.y >> 5), h = (int)(blockIdx.y & 31);
  const int hkv = h >> 2;

  const unsigned short* kbf = kbfg + (size_t)(b * HKV_ + hkv) * S_ * D_;
  const unsigned short* vtb = vtg + (size_t)(b * HKV_ + hkv) * D_ * S_;

  const f32x4 zero4 = {0.f, 0.f, 0.f, 0.f};
  const float NEG_INF = -__builtin_huge_valf();

  // ---- async staging of one K/Vt tile pair into buffer `buf` ----
  // K chunk swizzle: phys chunk pc of row kr holds logical pc^(kr&15).
  // V chunk swizzle: phys chunk pc of row dr holds logical pc^((dr>>1)&3).
  auto stage = [&](int kt, int buf) {
#pragma unroll
    for (int j = 0; j < 2; ++j) {
      int si = wave * 128 + j * 64 + lane;
      int kr = si >> 4, pc = si & 15;
      int lc = pc ^ (kr & 15);
      load_lds16(kbf + (size_t)(kt * 32 + kr) * D_ + lc * 8,
                 &KL[buf][(wave * 128 + j * 64) * 8]);
    }
#pragma unroll
    for (int j = 0; j < 2; ++j) {
      int si = wave * 128 + j * 64 + lane;
      int dr = si >> 2, pc = si & 3;
      int lc = pc ^ ((dr >> 1) & 3);
      load_lds16(vtb + (size_t)dr * S_ + kt * 32 + lc * 8,
                 &VL[buf][(wave * 128 + j * 64) * 8]);
    }
  };

  for (int ph = 0; ph < 2; ++ph) {
    const int qb = ph ? (31 - xb) : xb;
    const int qbase = qb * 64 + wave * 16;  // this wave's 16 q rows

    // Q fragments (A-layout), pre-scaled by COEF -> exp arg = 1 subtract.
    u16x8 qf[4];
#pragma unroll
    for (int ch = 0; ch < 4; ++ch) {
      const float* p = qg + (size_t)(b * S_ + qbase + l15) * (H_ * D_) +
                       h * D_ + ch * 32 + quad * 8;
      f32x4 x0 = *(const f32x4*)p;
      f32x4 x1 = *(const f32x4*)(p + 4);
      u16x8 t;
      t[0] = f2bf(x0[0] * COEF); t[1] = f2bf(x0[1] * COEF);
      t[2] = f2bf(x0[2] * COEF); t[3] = f2bf(x0[3] * COEF);
      t[4] = f2bf(x1[0] * COEF); t[5] = f2bf(x1[1] * COEF);
      t[6] = f2bf(x1[2] * COEF); t[7] = f2bf(x1[3] * COEF);
      qf[ch] = t;
    }

    f32x4 acc[8];
#pragma unroll
    for (int dt = 0; dt < 8; ++dt) acc[dt] = zero4;
    f32x4 mrow = {NEG_INF, NEG_INF, NEG_INF, NEG_INF};
    f32x4 lrow = zero4;

    const int nkt = qb * 2 + 2;  // always even

    stage(0, 0);
    __syncthreads();  // drains vmcnt: tile 0 resident

    for (int kt = 0; kt < nkt; ++kt) {
      const int cur = kt & 1;
      if (kt + 1 < nkt) stage(kt + 1, cur ^ 1);  // async, lands under compute

      if (kt * 32 <= qbase + 15) {  // wave-uniform: skip fully-masked tiles
        // ---- QK^T: 16 q-rows x 32 k-cols (log2-domain scores) ----
        f32x4 sc[2] = {zero4, zero4};
#pragma unroll
        for (int h2 = 0; h2 < 2; ++h2) {
          const int row = h2 * 16 + l15;
#pragma unroll
          for (int ch = 0; ch < 4; ++ch) {
            const int pc = (ch * 4 + quad) ^ l15;  // un-swizzle
            u16x8 kf = *(const u16x8*)&KL[cur][row * D_ + pc * 8];
            sc[h2] = MFMA16(__builtin_bit_cast(bf16x8, qf[ch]),
                            __builtin_bit_cast(bf16x8, kf), sc[h2]);
          }
        }
        const int kb0 = kt * 32;
        // causal mask (boundary tiles only)
#pragma unroll
        for (int h2 = 0; h2 < 2; ++h2) {
          if (kb0 + h2 * 16 + 15 > qbase) {
            int kgp = kb0 + h2 * 16 + l15;
#pragma unroll
            for (int r = 0; r < 4; ++r) {
              int qgp = qbase + quad * 4 + r;
              if (kgp > qgp) sc[h2][r] = NEG_INF;
            }
          }
        }
        // ---- online softmax (16-lane DPP rows; 4 rows/lane in regs) ----
        f32x4 mold = mrow, alpha;
#pragma unroll
        for (int r = 0; r < 4; ++r) {
          float mt = rowmax16(fmaxf(sc[0][r], sc[1][r]));
          float mn = fmaxf(mold[r], mt);
          mrow[r] = mn;
          alpha[r] = EXP2F(mold[r] - mn);
          float p0 = EXP2F(sc[0][r] - mn);
          float p1 = EXP2F(sc[1][r] - mn);
          sc[0][r] = p0;
          sc[1][r] = p1;
          lrow[r] = lrow[r] * alpha[r] + rowsum16(p0 + p1);
        }
#pragma unroll
        for (int dt = 0; dt < 8; ++dt)
#pragma unroll
          for (int r = 0; r < 4; ++r) acc[dt][r] *= alpha[r];
        // P: C-layout -> LDS bf16 (even lanes pack (k,k+1) via quad_perm)
#pragma unroll
        for (int h2 = 0; h2 < 2; ++h2)
#pragma unroll
          for (int r = 0; r < 4; ++r) {
            float mine = sc[h2][r];
            float nb = dppf<0xB1>(mine);  // value from lane^1
            if (!(l15 & 1)) {
              unsigned int w =
                  (unsigned int)f2bf(mine) | ((unsigned int)f2bf(nb) << 16);
              *(unsigned int*)&PL[wave][(quad * 4 + r) * PSTR + h2 * 16 + l15] = w;
            }
          }
        // ---- PV: A = P (A-layout from LDS), B = Vt (swizzled chunks) ----
        u16x8 pf = *(const u16x8*)&PL[wave][l15 * PSTR + quad * 8];
        bf16x8 pb = __builtin_bit_cast(bf16x8, pf);
        const int vsw = (quad ^ ((l15 >> 1) & 3)) * 8;  // un-swizzle V chunk
#pragma unroll
        for (int dt = 0; dt < 8; ++dt) {
          u16x8 vf = *(const u16x8*)&VL[cur][(dt * 16 + l15) * 32 + vsw];
          acc[dt] = MFMA16(pb, __builtin_bit_cast(bf16x8, vf), acc[dt]);
        }
      }
      __syncthreads();  // drains vmcnt (next tile resident) + publishes bufs
    }

    // ---- epilogue: O /= l, store fp32 (no LDS -> safe across phases) ----
    f32x4 inv;
#pragma unroll
    for (int r = 0; r < 4; ++r) inv[r] = 1.0f / lrow[r];
#pragma unroll
    for (int dt = 0; dt < 8; ++dt)
#pragma unroll
      for (int r = 0; r < 4; ++r)
        outg[(size_t)(b * S_ + qbase + quad * 4 + r) * (H_ * D_) +
             h * D_ + dt * 16 + l15] = acc[dt][r] * inv[r];
  }
}

extern "C" void kernel_launch(void* const* d_in, const int* in_sizes, int n_in,
                              void* d_out, int out_size, void* d_ws,
                              size_t ws_size, hipStream_t stream) {
  const float* q = (const float*)d_in[0];
  const float* k = (const float*)d_in[1];
  const float* v = (const float*)d_in[2];
  float* out = (float*)d_out;
  unsigned short* kws = (unsigned short*)d_ws;               // 8 MB Kbf
  unsigned short* vtws = kws + (size_t)B_ * HKV_ * S_ * D_;  // 8 MB Vt

  k_convert_kernel<<<(B_ * S_ * HKV_ * D_ / 8) / 256, 256, 0, stream>>>(k, kws);

  dim3 g1(S_ / 64, D_ / 32, B_ * HKV_);
  vt_transpose_kernel<<<g1, 256, 0, stream>>>(v, vtws);

  dim3 g2(16, B_ * H_);  // 16 x 64 = 1024 uniform blocks (68 k-iters each)
  attn_kernel<<<g2, 256, 0, stream>>>(q, kws, vtws, out);
}